// Round 5
// baseline (469.818 us; speedup 1.0000x reference)
//
#include <hip/hip_runtime.h>
#include <hip/hip_fp16.h>

#define RLC 256            // R*L*C = 8*4*8
#define BUCKET 32          // payload slots per node; overflow -> list
#define OVF_CAP 65536
#define NXCD 8
#define SCAN_BLOCK 256
#define SCAN_ITEMS 4

typedef float  vfloat4 __attribute__((ext_vector_type(4)));
typedef unsigned int vuint2 __attribute__((ext_vector_type(2)));

__device__ __forceinline__ float fast_exp2(float x) {
#if __has_builtin(__builtin_amdgcn_exp2f)
    return __builtin_amdgcn_exp2f(x);     // raw v_exp_f32, no libm fixup
#else
    return __expf(x * 0.6931471805599453f);
#endif
}

// round-to-nearest-even fp32 -> bf16 bits
__device__ __forceinline__ unsigned int bfr(float f) {
    unsigned int u = __float_as_uint(f);
    return (u + 0x7fffu + ((u >> 16) & 1u)) >> 16;
}

// NT 16B load via native clang vector (HIP float4 is a struct, rejected)
__device__ __forceinline__ vfloat4 nt_load_f4(const float4* p) {
    return __builtin_nontemporal_load((const vfloat4*)p);
}

#define LOG2E 1.4426950408889634f

// ===========================================================================
// TIER 1: XCD-partitioned fused cast+build, barrier-free scalar gather
// ===========================================================================

// Build is XCD-partitioned: block b (b < nb_build) owns dst partition b&7 and
// edge chunk b>>3; workgroups round-robin across the 8 XCDs so each
// partition's counts (50 KB) + payload slice (3.2 MB) stay in ONE XCD's L2.
// Cast blocks stream 153 MB — with normal accesses they evicted the payload
// lines (WRITE_SIZE stuck at ~148 MB) and the edge arrays (FETCH +91 MB,
// round 3). Cast is therefore fully NON-TEMPORAL (sequential stream,
// write-combines fine); edge src/len/cf are loaded coalesced+unconditional
// (the matched-only scalar loads touched every 64B line per partition
// anyway). Correctness does not depend on the XCD mapping, only locality.
__global__ __launch_bounds__(256) void build_cast_kernel(
    const int* __restrict__ edge_index,
    const float* __restrict__ edge_len,
    const float* __restrict__ cutoff_fn,
    int* __restrict__ counts,
    int2* __restrict__ payload,
    int4* __restrict__ ovf,
    int* __restrict__ ovf_cnt,
    int n_edges,
    const float4* __restrict__ nf_in,
    uint2* __restrict__ nfbT,
    int nr,
    int nb_build,
    int n_nodes)
{
    if ((int)blockIdx.x < nb_build) {
        // ---- build: partitioned histogram + bucket scatter ----
        int part  = blockIdx.x & (NXCD - 1);
        int chunk = blockIdx.x >> 3;
        int base  = (chunk * 256 + threadIdx.x) * 4;   // 4 edges per thread
        if (base >= n_edges) return;
        int plo = (int)((long)part * n_nodes / NXCD);
        int phi = (int)((long)(part + 1) * n_nodes / NXCD);

        int d[4], s[4];
        float el[4], cf[4];
        if (base + 4 <= n_edges) {
            int4 dv = *(const int4*)(edge_index + n_edges + base);
            int4 sv = *(const int4*)(edge_index + base);
            float4 lv = *(const float4*)(edge_len + base);
            float4 cv = *(const float4*)(cutoff_fn + base);
            d[0] = dv.x; d[1] = dv.y; d[2] = dv.z; d[3] = dv.w;
            s[0] = sv.x; s[1] = sv.y; s[2] = sv.z; s[3] = sv.w;
            el[0] = lv.x; el[1] = lv.y; el[2] = lv.z; el[3] = lv.w;
            cf[0] = cv.x; cf[1] = cv.y; cf[2] = cv.z; cf[3] = cv.w;
        } else {
            #pragma unroll
            for (int k = 0; k < 4; ++k) {
                bool ok = (base + k < n_edges);
                d[k]  = ok ? edge_index[n_edges + base + k] : -1;
                s[k]  = ok ? edge_index[base + k] : 0;
                el[k] = ok ? edge_len[base + k] : 0.f;
                cf[k] = ok ? cutoff_fn[base + k] : 0.f;
            }
        }

        unsigned int pk[4];
        #pragma unroll
        for (int k = 0; k < 4; ++k) {
            unsigned int hnl = __half_as_ushort(__float2half(-el[k]));
            unsigned int hcf = __half_as_ushort(__float2half(cf[k]));
            pk[k] = (hcf << 16) | hnl;
        }

        #pragma unroll
        for (int k = 0; k < 4; ++k) {
            int dst = d[k];
            if (dst < plo || dst >= phi) continue;   // not my partition
            int r = atomicAdd(&counts[dst], 1);
            if (r < BUCKET) {
                payload[(size_t)dst * BUCKET + r] = make_int2(s[k], (int)pk[k]);
            } else {
                int o = atomicAdd(ovf_cnt, 1);
                if (o < OVF_CAP) ovf[o] = make_int4(dst, s[k], (int)pk[k], 0);
            }
        }
    } else {
        // ---- cast: fp32 [r][l][c] -> bf16 [r][c][l], thread per (node,r).
        // Fully non-temporal: pure stream, keep L2/L3 for build's working set.
        int i = (blockIdx.x - nb_build) * 256 + threadIdx.x;
        if (i >= nr) return;
        const float4* p = nf_in + (size_t)i * 8;
        float v[32];
        #pragma unroll
        for (int q = 0; q < 8; ++q) {
            vfloat4 t = nt_load_f4(p + q);
            v[4*q+0] = t.x; v[4*q+1] = t.y; v[4*q+2] = t.z; v[4*q+3] = t.w;
        }
        vuint2* o = (vuint2*)(nfbT + (size_t)i * 8);
        #pragma unroll
        for (int c = 0; c < 8; ++c) {
            unsigned int lo = bfr(v[0*8+c]) | (bfr(v[1*8+c]) << 16);
            unsigned int hi = bfr(v[2*8+c]) | (bfr(v[3*8+c]) << 16);
            vuint2 w; w.x = lo; w.y = hi;
            __builtin_nontemporal_store(w, o + c);
        }
    }
}

// One wave per node; lane = r*8+c owns the 4 l-elements (shared decay).
// Payload read per edge is wave-uniform -> scalar (s_load) broadcast; no LDS,
// no __syncthreads, waves fully decoupled.
__global__ __launch_bounds__(256) void gather_bucket_kernel(
    const float* __restrict__ node_feat,     // fp32 [r][l][c] (self term)
    const unsigned short* __restrict__ nfbT, // bf16 [r][c][l]
    const int2* __restrict__ payload,
    const float* __restrict__ prefactor,     // [r][c] = 64
    const float* __restrict__ invr0,         // [r][c] = 64
    const float* __restrict__ coef_p,
    const int* __restrict__ counts,
    float* __restrict__ out,
    int n_nodes)
{
    int wave = threadIdx.x >> 6;
    int lane = threadIdx.x & 63;
    int node = blockIdx.x * 4 + wave;
    if (node >= n_nodes) return;

    float iv = invr0[lane] * LOG2E;
    float pf = prefactor[lane];
    float coef = *coef_p;

    int r = lane >> 3, c = lane & 7;
    long obase = (long)node * RLC + r * 32 + c;

    int deg = counts[node];
    int m = deg < BUCKET ? deg : BUCKET;

    // streaming fp32 self-term: non-temporal, don't pollute L2/L3
    float a0 = __builtin_nontemporal_load(node_feat + obase)      * coef;
    float a1 = __builtin_nontemporal_load(node_feat + obase + 8)  * coef;
    float a2 = __builtin_nontemporal_load(node_feat + obase + 16) * coef;
    float a3 = __builtin_nontemporal_load(node_feat + obase + 24) * coef;

    const int2* pp = payload + (size_t)node * BUCKET;
    const unsigned short* tb = nfbT + lane * 4;

    #pragma unroll 4
    for (int it = 0; it < m; ++it) {
        int2 p = pp[it];                           // uniform -> scalar load
        int src = p.x;
        unsigned int pk = (unsigned int)p.y;
        float nl = __half2float(__ushort_as_half((unsigned short)(pk & 0xffff)));
        float cf = __half2float(__ushort_as_half((unsigned short)(pk >> 16)));
        float w = fast_exp2(nl * iv) * pf * cf;    // 1 exp / edge / lane
        uint2 raw = *(const uint2*)(tb + (size_t)src * RLC);
        float f0 = __uint_as_float(raw.x << 16);
        float f1 = __uint_as_float(raw.x & 0xffff0000u);
        float f2 = __uint_as_float(raw.y << 16);
        float f3 = __uint_as_float(raw.y & 0xffff0000u);
        a0 += w * f0; a1 += w * f1; a2 += w * f2; a3 += w * f3;
    }

    // streamed output: non-temporal, never re-read
    __builtin_nontemporal_store(a0, out + obase);
    __builtin_nontemporal_store(a1, out + obase + 8);
    __builtin_nontemporal_store(a2, out + obase + 16);
    __builtin_nontemporal_store(a3, out + obase + 24);
}

// Overflow edges: one wave per record, 4 atomics per lane. ~tens of records.
__global__ __launch_bounds__(256) void ovf_kernel(
    const unsigned short* __restrict__ nfbT,
    const float* __restrict__ prefactor,
    const float* __restrict__ invr0,
    const int4* __restrict__ ovf,
    const int* __restrict__ ovf_cnt,
    float* __restrict__ out)
{
    int gtid = blockIdx.x * blockDim.x + threadIdx.x;
    int wid  = gtid >> 6;
    int lane = gtid & 63;
    int nwaves = (gridDim.x * blockDim.x) >> 6;
    int n = *ovf_cnt;
    if (n > OVF_CAP) n = OVF_CAP;

    float iv = invr0[lane] * LOG2E;
    float pf = prefactor[lane];
    int r = lane >> 3, c = lane & 7;

    for (int i = wid; i < n; i += nwaves) {
        int4 rec = ovf[i];
        int dst = rec.x, src = rec.y, pk = rec.z;
        float nl = __half2float(__ushort_as_half((unsigned short)(pk & 0xffff)));
        float cf = __half2float(__ushort_as_half((unsigned short)(((unsigned int)pk) >> 16)));
        float w = fast_exp2(nl * iv) * pf * cf;
        uint2 raw = *(const uint2*)(nfbT + (size_t)src * RLC + lane * 4);
        float f0 = __uint_as_float(raw.x << 16);
        float f1 = __uint_as_float(raw.x & 0xffff0000u);
        float f2 = __uint_as_float(raw.y << 16);
        float f3 = __uint_as_float(raw.y & 0xffff0000u);
        float* o = out + (long)dst * RLC + r * 32 + c;
        atomicAdd(o,      w * f0);
        atomicAdd(o + 8,  w * f1);
        atomicAdd(o + 16, w * f2);
        atomicAdd(o + 24, w * f3);
    }
}

// ===========================================================================
// TIER 2: R6 CSR path (fallback if ws too small for buckets)
// ===========================================================================

__global__ __launch_bounds__(256) void cast_kernel(
    const float4* __restrict__ in, uint4* __restrict__ outp, int n8)
{
    int i = blockIdx.x * blockDim.x + threadIdx.x;
    if (i >= n8) return;
    float4 a = in[2 * i];
    float4 b = in[2 * i + 1];
    uint4 r;
    r.x = bfr(a.x) | (bfr(a.y) << 16);
    r.y = bfr(a.z) | (bfr(a.w) << 16);
    r.z = bfr(b.x) | (bfr(b.y) << 16);
    r.w = bfr(b.z) | (bfr(b.w) << 16);
    outp[i] = r;
}

__global__ __launch_bounds__(256) void hist_rank_kernel(
    const int* __restrict__ edge_index, int* __restrict__ counts,
    unsigned char* __restrict__ rank, int n_edges)
{
    int e = blockIdx.x * blockDim.x + threadIdx.x;
    if (e >= n_edges) return;
    int dst = edge_index[n_edges + e];
    int r = atomicAdd(&counts[dst], 1);
    rank[e] = (unsigned char)r;
}

__global__ __launch_bounds__(SCAN_BLOCK) void scan1_kernel(
    const int* __restrict__ in, int* __restrict__ out,
    int* __restrict__ blocksums, int n)
{
    __shared__ int tmp[SCAN_BLOCK];
    int t = threadIdx.x;
    int base = blockIdx.x * SCAN_BLOCK * SCAN_ITEMS + t * SCAN_ITEMS;
    int v[SCAN_ITEMS];
    int tot = 0;
    #pragma unroll
    for (int k = 0; k < SCAN_ITEMS; ++k) {
        int i = base + k;
        v[k] = (i < n) ? in[i] : 0;
        tot += v[k];
    }
    tmp[t] = tot;
    __syncthreads();
    int run = tot;
    for (int d = 1; d < SCAN_BLOCK; d <<= 1) {
        int x = (t >= d) ? tmp[t - d] : 0;
        __syncthreads();
        tmp[t] += x;
        __syncthreads();
    }
    int excl = tmp[t] - run;
    #pragma unroll
    for (int k = 0; k < SCAN_ITEMS; ++k) {
        int i = base + k;
        if (i < n) out[i] = excl;
        excl += v[k];
    }
    if (t == SCAN_BLOCK - 1) blocksums[blockIdx.x] = tmp[t];
}

__global__ __launch_bounds__(SCAN_BLOCK) void scan2_kernel(
    int* __restrict__ blocksums, int nb)
{
    __shared__ int tmp[SCAN_BLOCK];
    int t = threadIdx.x;
    int v = (t < nb) ? blocksums[t] : 0;
    tmp[t] = v;
    __syncthreads();
    for (int d = 1; d < SCAN_BLOCK; d <<= 1) {
        int x = (t >= d) ? tmp[t - d] : 0;
        __syncthreads();
        tmp[t] += x;
        __syncthreads();
    }
    if (t < nb) blocksums[t] = tmp[t] - v;
}

__global__ __launch_bounds__(256) void scan3_kernel(
    int* __restrict__ offsets, const int* __restrict__ blocksums,
    int n, int n_edges)
{
    int i = blockIdx.x * blockDim.x + threadIdx.x;
    if (i == 0) offsets[n] = n_edges;
    if (i >= n) return;
    offsets[i] += blocksums[i / (SCAN_BLOCK * SCAN_ITEMS)];
}

__global__ __launch_bounds__(256) void scatter_rank_kernel(
    const int* __restrict__ edge_index,
    const float* __restrict__ edge_len,
    const float* __restrict__ cutoff_fn,
    const int* __restrict__ offsets,
    const unsigned char* __restrict__ rank,
    int2* __restrict__ payload, int n_edges)
{
    int e = blockIdx.x * blockDim.x + threadIdx.x;
    if (e >= n_edges) return;
    int dst = edge_index[n_edges + e];
    int src = edge_index[e];
    unsigned int hnl = __half_as_ushort(__float2half(-edge_len[e]));
    unsigned int hcf = __half_as_ushort(__float2half(cutoff_fn[e]));
    int pos = offsets[dst] + (int)rank[e];
    payload[pos] = make_int2(src, (int)((hcf << 16) | hnl));
}

__global__ __launch_bounds__(256) void gather_kernel(
    const float* __restrict__ node_feat,
    const unsigned short* __restrict__ nfb,
    const int2* __restrict__ payload,
    const float* __restrict__ prefactor,
    const float* __restrict__ invr0,
    const float* __restrict__ coef_p,
    const int*  __restrict__ offsets,
    float* __restrict__ out,
    int n_nodes)
{
    int tid  = blockIdx.x * blockDim.x + threadIdx.x;
    int node = tid >> 6;
    int lane = threadIdx.x & 63;
    if (node >= n_nodes) return;

    int f0     = lane << 2;
    int rcbase = ((f0 >> 5) << 3) + (f0 & 7);

    float4 iv = *(const float4*)(invr0 + rcbase);
    iv.x *= LOG2E; iv.y *= LOG2E; iv.z *= LOG2E; iv.w *= LOG2E;
    const float4 pf = *(const float4*)(prefactor + rcbase);
    float coef = *coef_p;

    const float4 self = *(const float4*)(node_feat + (long)node * RLC + f0);
    float ax = self.x * coef, ay = self.y * coef,
          az = self.z * coef, aw = self.w * coef;

    int j   = offsets[node];
    int end = offsets[node + 1];

    for (int base = j; base < end; base += 64) {
        int idx = base + lane;
        int2 p = make_int2(0, 0);
        if (idx < end) p = payload[idx];
        int m = end - base;
        if (m > 64) m = 64;
        int psrc = p.x;
        int ppk  = p.y;

        #pragma unroll 4
        for (int it = 0; it < m; ++it) {
            int src = __shfl(psrc, it, 64);
            int pk  = __shfl(ppk,  it, 64);
            float nl = __half2float(__ushort_as_half((unsigned short)(pk & 0xffff)));
            float cf = __half2float(__ushort_as_half((unsigned short)(((unsigned int)pk) >> 16)));
            uint2 raw = *(const uint2*)(nfb + (long)src * RLC + f0);
            float fx = __uint_as_float(raw.x << 16);
            float fy = __uint_as_float(raw.x & 0xffff0000u);
            float fz = __uint_as_float(raw.y << 16);
            float fw = __uint_as_float(raw.y & 0xffff0000u);
            ax += fx * (fast_exp2(nl * iv.x) * pf.x * cf);
            ay += fy * (fast_exp2(nl * iv.y) * pf.y * cf);
            az += fz * (fast_exp2(nl * iv.z) * pf.z * cf);
            aw += fw * (fast_exp2(nl * iv.w) * pf.w * cf);
        }
    }

    *(float4*)(out + (long)node * RLC + f0) = make_float4(ax, ay, az, aw);
}

// ===========================================================================
// TIER 3: atomic scatter (no ws)
// ===========================================================================
__global__ __launch_bounds__(256) void init_out_kernel(
    const float4* __restrict__ nf4, float4* __restrict__ out4,
    const float* __restrict__ coef_p, int n4)
{
    int i = blockIdx.x * blockDim.x + threadIdx.x;
    if (i >= n4) return;
    float c = *coef_p;
    float4 v = nf4[i];
    out4[i] = make_float4(v.x * c, v.y * c, v.z * c, v.w * c);
}

__global__ __launch_bounds__(256) void edge_scatter_kernel(
    const float* __restrict__ node_feat,
    const float* __restrict__ edge_len,
    const float* __restrict__ cutoff_fn,
    const int*  __restrict__ edge_index,
    const float* __restrict__ prefactor,
    const float* __restrict__ invr0,
    float* __restrict__ out, int n_edges)
{
    int tid  = blockIdx.x * blockDim.x + threadIdx.x;
    int e    = tid >> 6;
    int lane = threadIdx.x & 63;
    if (e >= n_edges) return;
    int   src = edge_index[e];
    int   dst = edge_index[n_edges + e];
    float len = edge_len[e];
    float cf  = cutoff_fn[e];
    int f0     = lane << 2;
    int rcbase = ((f0 >> 5) << 3) + (f0 & 7);
    const float4 iv = *(const float4*)(invr0 + rcbase);
    const float4 pf = *(const float4*)(prefactor + rcbase);
    const float4 s  = *(const float4*)(node_feat + (long)src * RLC + f0);
    float nl = -len;
    float* o = out + (long)dst * RLC + f0;
    atomicAdd(o + 0, s.x * __expf(nl * iv.x) * pf.x * cf);
    atomicAdd(o + 1, s.y * __expf(nl * iv.y) * pf.y * cf);
    atomicAdd(o + 2, s.z * __expf(nl * iv.z) * pf.z * cf);
    atomicAdd(o + 3, s.w * __expf(nl * iv.w) * pf.w * cf);
}

extern "C" void kernel_launch(void* const* d_in, const int* in_sizes, int n_in,
                              void* d_out, int out_size, void* d_ws, size_t ws_size,
                              hipStream_t stream) {
    const float* node_feat  = (const float*)d_in[0];
    const float* edge_len   = (const float*)d_in[1];
    const float* cutoff_fn  = (const float*)d_in[2];
    const int*   edge_index = (const int*)d_in[3];
    const float* prefactor  = (const float*)d_in[4];
    const float* invr0      = (const float*)d_in[5];
    const float* coef_p     = (const float*)d_in[6];
    float* out = (float*)d_out;

    const int n_edges = in_sizes[1];
    const int n_feat  = in_sizes[0];
    const int n_nodes = n_feat / RLC;

    // TIER 1 layout: nfbT | payload | ovf | counts | ovf_cnt
    size_t need1 = (size_t)n_feat * 2
                 + (size_t)n_nodes * BUCKET * 8
                 + (size_t)OVF_CAP * 16
                 + (size_t)(n_nodes + 1) * 4;

    const int per_block = SCAN_BLOCK * SCAN_ITEMS;
    const int nb1 = (n_nodes + per_block - 1) / per_block;
    size_t need2 = (size_t)n_feat * 2
                 + (size_t)n_edges * 8
                 + ((size_t)(n_nodes + 1) + n_nodes + 256) * 4
                 + (size_t)n_edges;

    if (ws_size >= need1) {
        unsigned short* nfbT = (unsigned short*)d_ws;
        int2* payload = (int2*)(nfbT + n_feat);
        int4* ovf     = (int4*)(payload + (size_t)n_nodes * BUCKET);
        int*  counts  = (int*)(ovf + OVF_CAP);
        int*  ovf_cnt = counts + n_nodes;

        (void)hipMemsetAsync(counts, 0, (size_t)(n_nodes + 1) * sizeof(int), stream);

        int nr = n_nodes * 8;
        // 4 edges per thread, 1024 edges per block, x8 partitions
        int nb_build = NXCD * ((n_edges + 1023) / 1024);
        int nb_cast  = (nr + 255) / 256;
        build_cast_kernel<<<nb_build + nb_cast, 256, 0, stream>>>(
            edge_index, edge_len, cutoff_fn, counts, payload, ovf, ovf_cnt,
            n_edges, (const float4*)node_feat, (uint2*)nfbT, nr, nb_build,
            n_nodes);

        int gg = (n_nodes + 3) / 4;
        gather_bucket_kernel<<<gg, 256, 0, stream>>>(
            node_feat, nfbT, payload, prefactor, invr0, coef_p, counts,
            out, n_nodes);

        ovf_kernel<<<64, 256, 0, stream>>>(
            nfbT, prefactor, invr0, ovf, ovf_cnt, out);
    } else if (ws_size >= need2 && nb1 <= SCAN_BLOCK) {
        unsigned short* nfb = (unsigned short*)d_ws;
        int2* payload   = (int2*)(nfb + n_feat);
        int* offsets    = (int*)(payload + n_edges);
        int* counts     = offsets + (n_nodes + 1);
        int* blocksums  = counts + n_nodes;
        unsigned char* rank = (unsigned char*)(blocksums + 256);

        int n8 = n_feat / 8;
        cast_kernel<<<(n8 + 255) / 256, 256, 0, stream>>>(
            (const float4*)node_feat, (uint4*)nfb, n8);

        (void)hipMemsetAsync(counts, 0, (size_t)n_nodes * sizeof(int), stream);

        int eg = (n_edges + 255) / 256;
        hist_rank_kernel<<<eg, 256, 0, stream>>>(edge_index, counts, rank, n_edges);
        scan1_kernel<<<nb1, SCAN_BLOCK, 0, stream>>>(counts, offsets, blocksums, n_nodes);
        scan2_kernel<<<1, SCAN_BLOCK, 0, stream>>>(blocksums, nb1);
        int ng = (n_nodes + 255) / 256;
        scan3_kernel<<<ng, 256, 0, stream>>>(offsets, blocksums, n_nodes, n_edges);
        scatter_rank_kernel<<<eg, 256, 0, stream>>>(
            edge_index, edge_len, cutoff_fn, offsets, rank, payload, n_edges);

        long total = (long)n_nodes * 64;
        int gg = (int)((total + 255) / 256);
        gather_kernel<<<gg, 256, 0, stream>>>(
            node_feat, nfb, payload, prefactor, invr0, coef_p, offsets,
            out, n_nodes);
    } else {
        int n4 = n_feat / 4;
        init_out_kernel<<<(n4 + 255) / 256, 256, 0, stream>>>(
            (const float4*)node_feat, (float4*)out, coef_p, n4);
        long total_threads = (long)n_edges * 64;
        int grid = (int)((total_threads + 255) / 256);
        edge_scatter_kernel<<<grid, 256, 0, stream>>>(
            node_feat, edge_len, cutoff_fn, edge_index,
            prefactor, invr0, out, n_edges);
    }
}

// Round 6
// 422.573 us; speedup vs baseline: 1.1118x; 1.1118x over previous
//
#include <hip/hip_runtime.h>
#include <hip/hip_fp16.h>

#define RLC 256            // R*L*C = 8*4*8
#define BUCKET 32          // payload slots per node; overflow -> list
#define OVF_CAP 65536
#define NXCD 8
#define SCAN_BLOCK 256
#define SCAN_ITEMS 4

__device__ __forceinline__ float fast_exp2(float x) {
#if __has_builtin(__builtin_amdgcn_exp2f)
    return __builtin_amdgcn_exp2f(x);     // raw v_exp_f32, no libm fixup
#else
    return __expf(x * 0.6931471805599453f);
#endif
}

// round-to-nearest-even fp32 -> bf16 bits
__device__ __forceinline__ unsigned int bfr(float f) {
    unsigned int u = __float_as_uint(f);
    return (u + 0x7fffu + ((u >> 16) & 1u)) >> 16;
}

#define LOG2E 1.4426950408889634f

// ===========================================================================
// TIER 1: standalone XCD-partitioned build -> cast -> gather
//
// History (measured):
//  - fused build+cast, NT payload store: 183us, WRITE 151MB (NT 8B scatter
//    pushes full 64B lines to HBM). Reverted.
//  - fused, normal payload: 170us, WRITE 148MB (payload line ping-pong).
//  - + XCD partitioning: 145us, WRITE *still* 148MB -> partition slices
//    (3.2MB payload + 50KB counts per XCD L2) evicted by co-resident cast
//    blocks streaming 153MB.
//  - NT cast: WRITE 192MB (+44): NT store sends nfbT straight to HBM
//    instead of leaving it in write-back L3 for gather. Reverted.
//  => UNFUSE: build alone (slices stay L2-resident), cast alone right
//    before gather (table lands hot in L3).
// ===========================================================================

// Block b owns dst partition b&7 and edge chunk b>>3; workgroups round-robin
// across the 8 XCDs so partition p's counts+payload slice stays in ONE XCD's
// L2. Each partition re-scans dst (L3-served, 8x6.4MB). Correctness does not
// depend on the XCD mapping, only locality.
__global__ __launch_bounds__(256) void build_kernel(
    const int* __restrict__ edge_index,
    const float* __restrict__ edge_len,
    const float* __restrict__ cutoff_fn,
    int* __restrict__ counts,
    int2* __restrict__ payload,
    int4* __restrict__ ovf,
    int* __restrict__ ovf_cnt,
    int n_edges,
    int n_nodes)
{
    int part  = blockIdx.x & (NXCD - 1);
    int chunk = blockIdx.x >> 3;
    int base  = (chunk * 256 + threadIdx.x) * 4;   // 4 edges per thread
    if (base >= n_edges) return;
    int plo = (int)((long)part * n_nodes / NXCD);
    int phi = (int)((long)(part + 1) * n_nodes / NXCD);

    int d[4], s[4];
    float el[4], cf[4];
    if (base + 4 <= n_edges) {
        int4 dv = *(const int4*)(edge_index + n_edges + base);
        int4 sv = *(const int4*)(edge_index + base);
        float4 lv = *(const float4*)(edge_len + base);
        float4 cv = *(const float4*)(cutoff_fn + base);
        d[0] = dv.x; d[1] = dv.y; d[2] = dv.z; d[3] = dv.w;
        s[0] = sv.x; s[1] = sv.y; s[2] = sv.z; s[3] = sv.w;
        el[0] = lv.x; el[1] = lv.y; el[2] = lv.z; el[3] = lv.w;
        cf[0] = cv.x; cf[1] = cv.y; cf[2] = cv.z; cf[3] = cv.w;
    } else {
        #pragma unroll
        for (int k = 0; k < 4; ++k) {
            bool ok = (base + k < n_edges);
            d[k]  = ok ? edge_index[n_edges + base + k] : -1;
            s[k]  = ok ? edge_index[base + k] : 0;
            el[k] = ok ? edge_len[base + k] : 0.f;
            cf[k] = ok ? cutoff_fn[base + k] : 0.f;
        }
    }

    unsigned int pk[4];
    #pragma unroll
    for (int k = 0; k < 4; ++k) {
        unsigned int hnl = __half_as_ushort(__float2half(-el[k]));
        unsigned int hcf = __half_as_ushort(__float2half(cf[k]));
        pk[k] = (hcf << 16) | hnl;
    }

    #pragma unroll
    for (int k = 0; k < 4; ++k) {
        int dst = d[k];
        if (dst < plo || dst >= phi) continue;   // not my partition
        int r = atomicAdd(&counts[dst], 1);
        if (r < BUCKET) {
            payload[(size_t)dst * BUCKET + r] = make_int2(s[k], (int)pk[k]);
        } else {
            int o = atomicAdd(ovf_cnt, 1);
            if (o < OVF_CAP) ovf[o] = make_int4(dst, s[k], (int)pk[k], 0);
        }
    }
}

// Transposed cast: thread per (node,r). Reads 32 fp32 [l][c] (128B contig),
// writes 32 bf16 as [c][l] (64B contig). Normal stores: nfbT stays in
// write-back L3 and is hot for gather's first touch.
__global__ __launch_bounds__(256) void cast_t_kernel(
    const float4* __restrict__ in, uint2* __restrict__ outp, int nr)
{
    int i = blockIdx.x * blockDim.x + threadIdx.x;
    if (i >= nr) return;
    const float4* p = in + (size_t)i * 8;
    float v[32];
    #pragma unroll
    for (int q = 0; q < 8; ++q) {
        float4 t = p[q];
        v[4*q+0] = t.x; v[4*q+1] = t.y; v[4*q+2] = t.z; v[4*q+3] = t.w;
    }
    uint2* o = outp + (size_t)i * 8;
    #pragma unroll
    for (int c = 0; c < 8; ++c) {
        unsigned int lo = bfr(v[0*8+c]) | (bfr(v[1*8+c]) << 16);
        unsigned int hi = bfr(v[2*8+c]) | (bfr(v[3*8+c]) << 16);
        o[c] = make_uint2(lo, hi);
    }
}

// One wave per node; lane = r*8+c owns the 4 l-elements (shared decay).
// Payload read per edge is wave-uniform -> scalar (s_load) broadcast; no LDS,
// no __syncthreads, waves fully decoupled.
__global__ __launch_bounds__(256) void gather_bucket_kernel(
    const float* __restrict__ node_feat,     // fp32 [r][l][c] (self term)
    const unsigned short* __restrict__ nfbT, // bf16 [r][c][l]
    const int2* __restrict__ payload,
    const float* __restrict__ prefactor,     // [r][c] = 64
    const float* __restrict__ invr0,         // [r][c] = 64
    const float* __restrict__ coef_p,
    const int* __restrict__ counts,
    float* __restrict__ out,
    int n_nodes)
{
    int wave = threadIdx.x >> 6;
    int lane = threadIdx.x & 63;
    int node = blockIdx.x * 4 + wave;
    if (node >= n_nodes) return;

    float iv = invr0[lane] * LOG2E;
    float pf = prefactor[lane];
    float coef = *coef_p;

    int r = lane >> 3, c = lane & 7;
    long obase = (long)node * RLC + r * 32 + c;

    int deg = counts[node];
    int m = deg < BUCKET ? deg : BUCKET;

    // streaming fp32 self-term: non-temporal, don't pollute L2/L3
    float a0 = __builtin_nontemporal_load(node_feat + obase)      * coef;
    float a1 = __builtin_nontemporal_load(node_feat + obase + 8)  * coef;
    float a2 = __builtin_nontemporal_load(node_feat + obase + 16) * coef;
    float a3 = __builtin_nontemporal_load(node_feat + obase + 24) * coef;

    const int2* pp = payload + (size_t)node * BUCKET;
    const unsigned short* tb = nfbT + lane * 4;

    #pragma unroll 4
    for (int it = 0; it < m; ++it) {
        int2 p = pp[it];                           // uniform -> scalar load
        int src = p.x;
        unsigned int pk = (unsigned int)p.y;
        float nl = __half2float(__ushort_as_half((unsigned short)(pk & 0xffff)));
        float cf = __half2float(__ushort_as_half((unsigned short)(pk >> 16)));
        float w = fast_exp2(nl * iv) * pf * cf;    // 1 exp / edge / lane
        uint2 raw = *(const uint2*)(tb + (size_t)src * RLC);
        float f0 = __uint_as_float(raw.x << 16);
        float f1 = __uint_as_float(raw.x & 0xffff0000u);
        float f2 = __uint_as_float(raw.y << 16);
        float f3 = __uint_as_float(raw.y & 0xffff0000u);
        a0 += w * f0; a1 += w * f1; a2 += w * f2; a3 += w * f3;
    }

    // streamed output: non-temporal, never re-read
    __builtin_nontemporal_store(a0, out + obase);
    __builtin_nontemporal_store(a1, out + obase + 8);
    __builtin_nontemporal_store(a2, out + obase + 16);
    __builtin_nontemporal_store(a3, out + obase + 24);
}

// Overflow edges: one wave per record, 4 atomics per lane. ~tens of records.
__global__ __launch_bounds__(256) void ovf_kernel(
    const unsigned short* __restrict__ nfbT,
    const float* __restrict__ prefactor,
    const float* __restrict__ invr0,
    const int4* __restrict__ ovf,
    const int* __restrict__ ovf_cnt,
    float* __restrict__ out)
{
    int gtid = blockIdx.x * blockDim.x + threadIdx.x;
    int wid  = gtid >> 6;
    int lane = gtid & 63;
    int nwaves = (gridDim.x * blockDim.x) >> 6;
    int n = *ovf_cnt;
    if (n > OVF_CAP) n = OVF_CAP;

    float iv = invr0[lane] * LOG2E;
    float pf = prefactor[lane];
    int r = lane >> 3, c = lane & 7;

    for (int i = wid; i < n; i += nwaves) {
        int4 rec = ovf[i];
        int dst = rec.x, src = rec.y, pk = rec.z;
        float nl = __half2float(__ushort_as_half((unsigned short)(pk & 0xffff)));
        float cf = __half2float(__ushort_as_half((unsigned short)(((unsigned int)pk) >> 16)));
        float w = fast_exp2(nl * iv) * pf * cf;
        uint2 raw = *(const uint2*)(nfbT + (size_t)src * RLC + lane * 4);
        float f0 = __uint_as_float(raw.x << 16);
        float f1 = __uint_as_float(raw.x & 0xffff0000u);
        float f2 = __uint_as_float(raw.y << 16);
        float f3 = __uint_as_float(raw.y & 0xffff0000u);
        float* o = out + (long)dst * RLC + r * 32 + c;
        atomicAdd(o,      w * f0);
        atomicAdd(o + 8,  w * f1);
        atomicAdd(o + 16, w * f2);
        atomicAdd(o + 24, w * f3);
    }
}

// ===========================================================================
// TIER 2: R6 CSR path (fallback if ws too small for buckets)
// ===========================================================================

__global__ __launch_bounds__(256) void cast_kernel(
    const float4* __restrict__ in, uint4* __restrict__ outp, int n8)
{
    int i = blockIdx.x * blockDim.x + threadIdx.x;
    if (i >= n8) return;
    float4 a = in[2 * i];
    float4 b = in[2 * i + 1];
    uint4 r;
    r.x = bfr(a.x) | (bfr(a.y) << 16);
    r.y = bfr(a.z) | (bfr(a.w) << 16);
    r.z = bfr(b.x) | (bfr(b.y) << 16);
    r.w = bfr(b.z) | (bfr(b.w) << 16);
    outp[i] = r;
}

__global__ __launch_bounds__(256) void hist_rank_kernel(
    const int* __restrict__ edge_index, int* __restrict__ counts,
    unsigned char* __restrict__ rank, int n_edges)
{
    int e = blockIdx.x * blockDim.x + threadIdx.x;
    if (e >= n_edges) return;
    int dst = edge_index[n_edges + e];
    int r = atomicAdd(&counts[dst], 1);
    rank[e] = (unsigned char)r;
}

__global__ __launch_bounds__(SCAN_BLOCK) void scan1_kernel(
    const int* __restrict__ in, int* __restrict__ out,
    int* __restrict__ blocksums, int n)
{
    __shared__ int tmp[SCAN_BLOCK];
    int t = threadIdx.x;
    int base = blockIdx.x * SCAN_BLOCK * SCAN_ITEMS + t * SCAN_ITEMS;
    int v[SCAN_ITEMS];
    int tot = 0;
    #pragma unroll
    for (int k = 0; k < SCAN_ITEMS; ++k) {
        int i = base + k;
        v[k] = (i < n) ? in[i] : 0;
        tot += v[k];
    }
    tmp[t] = tot;
    __syncthreads();
    int run = tot;
    for (int d = 1; d < SCAN_BLOCK; d <<= 1) {
        int x = (t >= d) ? tmp[t - d] : 0;
        __syncthreads();
        tmp[t] += x;
        __syncthreads();
    }
    int excl = tmp[t] - run;
    #pragma unroll
    for (int k = 0; k < SCAN_ITEMS; ++k) {
        int i = base + k;
        if (i < n) out[i] = excl;
        excl += v[k];
    }
    if (t == SCAN_BLOCK - 1) blocksums[blockIdx.x] = tmp[t];
}

__global__ __launch_bounds__(SCAN_BLOCK) void scan2_kernel(
    int* __restrict__ blocksums, int nb)
{
    __shared__ int tmp[SCAN_BLOCK];
    int t = threadIdx.x;
    int v = (t < nb) ? blocksums[t] : 0;
    tmp[t] = v;
    __syncthreads();
    for (int d = 1; d < SCAN_BLOCK; d <<= 1) {
        int x = (t >= d) ? tmp[t - d] : 0;
        __syncthreads();
        tmp[t] += x;
        __syncthreads();
    }
    if (t < nb) blocksums[t] = tmp[t] - v;
}

__global__ __launch_bounds__(256) void scan3_kernel(
    int* __restrict__ offsets, const int* __restrict__ blocksums,
    int n, int n_edges)
{
    int i = blockIdx.x * blockDim.x + threadIdx.x;
    if (i == 0) offsets[n] = n_edges;
    if (i >= n) return;
    offsets[i] += blocksums[i / (SCAN_BLOCK * SCAN_ITEMS)];
}

__global__ __launch_bounds__(256) void scatter_rank_kernel(
    const int* __restrict__ edge_index,
    const float* __restrict__ edge_len,
    const float* __restrict__ cutoff_fn,
    const int* __restrict__ offsets,
    const unsigned char* __restrict__ rank,
    int2* __restrict__ payload, int n_edges)
{
    int e = blockIdx.x * blockDim.x + threadIdx.x;
    if (e >= n_edges) return;
    int dst = edge_index[n_edges + e];
    int src = edge_index[e];
    unsigned int hnl = __half_as_ushort(__float2half(-edge_len[e]));
    unsigned int hcf = __half_as_ushort(__float2half(cutoff_fn[e]));
    int pos = offsets[dst] + (int)rank[e];
    payload[pos] = make_int2(src, (int)((hcf << 16) | hnl));
}

__global__ __launch_bounds__(256) void gather_kernel(
    const float* __restrict__ node_feat,
    const unsigned short* __restrict__ nfb,
    const int2* __restrict__ payload,
    const float* __restrict__ prefactor,
    const float* __restrict__ invr0,
    const float* __restrict__ coef_p,
    const int*  __restrict__ offsets,
    float* __restrict__ out,
    int n_nodes)
{
    int tid  = blockIdx.x * blockDim.x + threadIdx.x;
    int node = tid >> 6;
    int lane = threadIdx.x & 63;
    if (node >= n_nodes) return;

    int f0     = lane << 2;
    int rcbase = ((f0 >> 5) << 3) + (f0 & 7);

    float4 iv = *(const float4*)(invr0 + rcbase);
    iv.x *= LOG2E; iv.y *= LOG2E; iv.z *= LOG2E; iv.w *= LOG2E;
    const float4 pf = *(const float4*)(prefactor + rcbase);
    float coef = *coef_p;

    const float4 self = *(const float4*)(node_feat + (long)node * RLC + f0);
    float ax = self.x * coef, ay = self.y * coef,
          az = self.z * coef, aw = self.w * coef;

    int j   = offsets[node];
    int end = offsets[node + 1];

    for (int base = j; base < end; base += 64) {
        int idx = base + lane;
        int2 p = make_int2(0, 0);
        if (idx < end) p = payload[idx];
        int m = end - base;
        if (m > 64) m = 64;
        int psrc = p.x;
        int ppk  = p.y;

        #pragma unroll 4
        for (int it = 0; it < m; ++it) {
            int src = __shfl(psrc, it, 64);
            int pk  = __shfl(ppk,  it, 64);
            float nl = __half2float(__ushort_as_half((unsigned short)(pk & 0xffff)));
            float cf = __half2float(__ushort_as_half((unsigned short)(((unsigned int)pk) >> 16)));
            uint2 raw = *(const uint2*)(nfb + (long)src * RLC + f0);
            float fx = __uint_as_float(raw.x << 16);
            float fy = __uint_as_float(raw.x & 0xffff0000u);
            float fz = __uint_as_float(raw.y << 16);
            float fw = __uint_as_float(raw.y & 0xffff0000u);
            ax += fx * (fast_exp2(nl * iv.x) * pf.x * cf);
            ay += fy * (fast_exp2(nl * iv.y) * pf.y * cf);
            az += fz * (fast_exp2(nl * iv.z) * pf.z * cf);
            aw += fw * (fast_exp2(nl * iv.w) * pf.w * cf);
        }
    }

    *(float4*)(out + (long)node * RLC + f0) = make_float4(ax, ay, az, aw);
}

// ===========================================================================
// TIER 3: atomic scatter (no ws)
// ===========================================================================
__global__ __launch_bounds__(256) void init_out_kernel(
    const float4* __restrict__ nf4, float4* __restrict__ out4,
    const float* __restrict__ coef_p, int n4)
{
    int i = blockIdx.x * blockDim.x + threadIdx.x;
    if (i >= n4) return;
    float c = *coef_p;
    float4 v = nf4[i];
    out4[i] = make_float4(v.x * c, v.y * c, v.z * c, v.w * c);
}

__global__ __launch_bounds__(256) void edge_scatter_kernel(
    const float* __restrict__ node_feat,
    const float* __restrict__ edge_len,
    const float* __restrict__ cutoff_fn,
    const int*  __restrict__ edge_index,
    const float* __restrict__ prefactor,
    const float* __restrict__ invr0,
    float* __restrict__ out, int n_edges)
{
    int tid  = blockIdx.x * blockDim.x + threadIdx.x;
    int e    = tid >> 6;
    int lane = threadIdx.x & 63;
    if (e >= n_edges) return;
    int   src = edge_index[e];
    int   dst = edge_index[n_edges + e];
    float len = edge_len[e];
    float cf  = cutoff_fn[e];
    int f0     = lane << 2;
    int rcbase = ((f0 >> 5) << 3) + (f0 & 7);
    const float4 iv = *(const float4*)(invr0 + rcbase);
    const float4 pf = *(const float4*)(prefactor + rcbase);
    const float4 s  = *(const float4*)(node_feat + (long)src * RLC + f0);
    float nl = -len;
    float* o = out + (long)dst * RLC + f0;
    atomicAdd(o + 0, s.x * __expf(nl * iv.x) * pf.x * cf);
    atomicAdd(o + 1, s.y * __expf(nl * iv.y) * pf.y * cf);
    atomicAdd(o + 2, s.z * __expf(nl * iv.z) * pf.z * cf);
    atomicAdd(o + 3, s.w * __expf(nl * iv.w) * pf.w * cf);
}

extern "C" void kernel_launch(void* const* d_in, const int* in_sizes, int n_in,
                              void* d_out, int out_size, void* d_ws, size_t ws_size,
                              hipStream_t stream) {
    const float* node_feat  = (const float*)d_in[0];
    const float* edge_len   = (const float*)d_in[1];
    const float* cutoff_fn  = (const float*)d_in[2];
    const int*   edge_index = (const int*)d_in[3];
    const float* prefactor  = (const float*)d_in[4];
    const float* invr0      = (const float*)d_in[5];
    const float* coef_p     = (const float*)d_in[6];
    float* out = (float*)d_out;

    const int n_edges = in_sizes[1];
    const int n_feat  = in_sizes[0];
    const int n_nodes = n_feat / RLC;

    // TIER 1 layout: nfbT | payload | ovf | counts | ovf_cnt
    size_t need1 = (size_t)n_feat * 2
                 + (size_t)n_nodes * BUCKET * 8
                 + (size_t)OVF_CAP * 16
                 + (size_t)(n_nodes + 1) * 4;

    const int per_block = SCAN_BLOCK * SCAN_ITEMS;
    const int nb1 = (n_nodes + per_block - 1) / per_block;
    size_t need2 = (size_t)n_feat * 2
                 + (size_t)n_edges * 8
                 + ((size_t)(n_nodes + 1) + n_nodes + 256) * 4
                 + (size_t)n_edges;

    if (ws_size >= need1) {
        unsigned short* nfbT = (unsigned short*)d_ws;
        int2* payload = (int2*)(nfbT + n_feat);
        int4* ovf     = (int4*)(payload + (size_t)n_nodes * BUCKET);
        int*  counts  = (int*)(ovf + OVF_CAP);
        int*  ovf_cnt = counts + n_nodes;

        (void)hipMemsetAsync(counts, 0, (size_t)(n_nodes + 1) * sizeof(int), stream);

        // 1) build alone: partition slices stay resident in their XCD L2
        int nb_build = NXCD * ((n_edges + 1023) / 1024);
        build_kernel<<<nb_build, 256, 0, stream>>>(
            edge_index, edge_len, cutoff_fn, counts, payload, ovf, ovf_cnt,
            n_edges, n_nodes);

        // 2) cast alone: streams without competing with build's working set;
        //    nfbT lands hot in L3 right before gather reads it
        int nr = n_nodes * 8;
        cast_t_kernel<<<(nr + 255) / 256, 256, 0, stream>>>(
            (const float4*)node_feat, (uint2*)nfbT, nr);

        // 3) gather
        int gg = (n_nodes + 3) / 4;
        gather_bucket_kernel<<<gg, 256, 0, stream>>>(
            node_feat, nfbT, payload, prefactor, invr0, coef_p, counts,
            out, n_nodes);

        ovf_kernel<<<64, 256, 0, stream>>>(
            nfbT, prefactor, invr0, ovf, ovf_cnt, out);
    } else if (ws_size >= need2 && nb1 <= SCAN_BLOCK) {
        unsigned short* nfb = (unsigned short*)d_ws;
        int2* payload   = (int2*)(nfb + n_feat);
        int* offsets    = (int*)(payload + n_edges);
        int* counts     = offsets + (n_nodes + 1);
        int* blocksums  = counts + n_nodes;
        unsigned char* rank = (unsigned char*)(blocksums + 256);

        int n8 = n_feat / 8;
        cast_kernel<<<(n8 + 255) / 256, 256, 0, stream>>>(
            (const float4*)node_feat, (uint4*)nfb, n8);

        (void)hipMemsetAsync(counts, 0, (size_t)n_nodes * sizeof(int), stream);

        int eg = (n_edges + 255) / 256;
        hist_rank_kernel<<<eg, 256, 0, stream>>>(edge_index, counts, rank, n_edges);
        scan1_kernel<<<nb1, SCAN_BLOCK, 0, stream>>>(counts, offsets, blocksums, n_nodes);
        scan2_kernel<<<1, SCAN_BLOCK, 0, stream>>>(blocksums, nb1);
        int ng = (n_nodes + 255) / 256;
        scan3_kernel<<<ng, 256, 0, stream>>>(offsets, blocksums, n_nodes, n_edges);
        scatter_rank_kernel<<<eg, 256, 0, stream>>>(
            edge_index, edge_len, cutoff_fn, offsets, rank, payload, n_edges);

        long total = (long)n_nodes * 64;
        int gg = (int)((total + 255) / 256);
        gather_kernel<<<gg, 256, 0, stream>>>(
            node_feat, nfb, payload, prefactor, invr0, coef_p, offsets,
            out, n_nodes);
    } else {
        int n4 = n_feat / 4;
        init_out_kernel<<<(n4 + 255) / 256, 256, 0, stream>>>(
            (const float4*)node_feat, (float4*)out, coef_p, n4);
        long total_threads = (long)n_edges * 64;
        int grid = (int)((total_threads + 255) / 256);
        edge_scatter_kernel<<<grid, 256, 0, stream>>>(
            node_feat, edge_len, cutoff_fn, edge_index,
            prefactor, invr0, out, n_edges);
    }
}

// Round 8
// 411.076 us; speedup vs baseline: 1.1429x; 1.0280x over previous
//
#include <hip/hip_runtime.h>
#include <hip/hip_fp16.h>

#define RLC 256            // R*L*C = 8*4*8
#define BUCKET 32          // payload slots per node; overflow -> list
#define OVF_CAP 65536
#define NXCD 8
#define SCAN_BLOCK 256
#define SCAN_ITEMS 4

__device__ __forceinline__ float fast_exp2(float x) {
#if __has_builtin(__builtin_amdgcn_exp2f)
    return __builtin_amdgcn_exp2f(x);     // raw v_exp_f32, no libm fixup
#else
    return __expf(x * 0.6931471805599453f);
#endif
}

// round-to-nearest-even fp32 -> bf16 bits
__device__ __forceinline__ unsigned int bfr(float f) {
    unsigned int u = __float_as_uint(f);
    return (u + 0x7fffu + ((u >> 16) & 1u)) >> 16;
}

#define LOG2E 1.4426950408889634f

// ===========================================================================
// TIER 1: cast(+zero) -> build -> gather(+ovf)   [3 dispatches]
//
// History (measured):
//  - NT payload store: WRITE +87MB (8B NT scatter -> full-line HBM push).
//  - XCD-partitioned build: 170->145us fused; standalone ~110.
//  - NT cast stores: WRITE +44MB (nfbT pushed to HBM instead of L3;
//    gather re-fetches cold). nfbT MUST stay cache-resident.
//  - unfuse build/cast: wall 429->423.
//  - wall - sum(kernels) ~ 150us across ALL rounds => ~25-30us fixed cost
//    per dispatch slot. This round: 5 dispatches -> 3.
//  (round 7 bench was an infra failure — identical resubmit)
// ===========================================================================

// Transposed cast: thread per (node,r). Reads 32 fp32 [l][c] (128B contig),
// writes 32 bf16 as [c][l] (64B contig). Normal stores: nfbT stays in
// write-back L3 (build's unique footprint is only ~25MB, nfbT survives it).
// Also zeroes counts[0..nz) — replaces the hipMemsetAsync dispatch.
__global__ __launch_bounds__(256) void cast_t_kernel(
    const float4* __restrict__ in, uint2* __restrict__ outp, int nr,
    int* __restrict__ cz, int nz)
{
    int i = blockIdx.x * blockDim.x + threadIdx.x;
    if (i < nz) cz[i] = 0;
    if (i >= nr) return;
    const float4* p = in + (size_t)i * 8;
    float v[32];
    #pragma unroll
    for (int q = 0; q < 8; ++q) {
        float4 t = p[q];
        v[4*q+0] = t.x; v[4*q+1] = t.y; v[4*q+2] = t.z; v[4*q+3] = t.w;
    }
    uint2* o = outp + (size_t)i * 8;
    #pragma unroll
    for (int c = 0; c < 8; ++c) {
        unsigned int lo = bfr(v[0*8+c]) | (bfr(v[1*8+c]) << 16);
        unsigned int hi = bfr(v[2*8+c]) | (bfr(v[3*8+c]) << 16);
        o[c] = make_uint2(lo, hi);
    }
}

// Block b owns dst partition b&7 and edge chunk b>>3; workgroups round-robin
// across the 8 XCDs so partition p's counts+payload slice stays in ONE XCD's
// L2. Each partition re-scans the edge arrays (L3-served: unique 25.6MB set).
// Correctness does not depend on the XCD mapping, only locality.
__global__ __launch_bounds__(256) void build_kernel(
    const int* __restrict__ edge_index,
    const float* __restrict__ edge_len,
    const float* __restrict__ cutoff_fn,
    int* __restrict__ counts,
    int2* __restrict__ payload,
    int4* __restrict__ ovf,
    int* __restrict__ ovf_cnt,
    int n_edges,
    int n_nodes)
{
    int part  = blockIdx.x & (NXCD - 1);
    int chunk = blockIdx.x >> 3;
    int base  = (chunk * 256 + threadIdx.x) * 4;   // 4 edges per thread
    if (base >= n_edges) return;
    int plo = (int)((long)part * n_nodes / NXCD);
    int phi = (int)((long)(part + 1) * n_nodes / NXCD);

    int d[4], s[4];
    float el[4], cf[4];
    if (base + 4 <= n_edges) {
        int4 dv = *(const int4*)(edge_index + n_edges + base);
        int4 sv = *(const int4*)(edge_index + base);
        float4 lv = *(const float4*)(edge_len + base);
        float4 cv = *(const float4*)(cutoff_fn + base);
        d[0] = dv.x; d[1] = dv.y; d[2] = dv.z; d[3] = dv.w;
        s[0] = sv.x; s[1] = sv.y; s[2] = sv.z; s[3] = sv.w;
        el[0] = lv.x; el[1] = lv.y; el[2] = lv.z; el[3] = lv.w;
        cf[0] = cv.x; cf[1] = cv.y; cf[2] = cv.z; cf[3] = cv.w;
    } else {
        #pragma unroll
        for (int k = 0; k < 4; ++k) {
            bool ok = (base + k < n_edges);
            d[k]  = ok ? edge_index[n_edges + base + k] : -1;
            s[k]  = ok ? edge_index[base + k] : 0;
            el[k] = ok ? edge_len[base + k] : 0.f;
            cf[k] = ok ? cutoff_fn[base + k] : 0.f;
        }
    }

    unsigned int pk[4];
    #pragma unroll
    for (int k = 0; k < 4; ++k) {
        unsigned int hnl = __half_as_ushort(__float2half(-el[k]));
        unsigned int hcf = __half_as_ushort(__float2half(cf[k]));
        pk[k] = (hcf << 16) | hnl;
    }

    #pragma unroll
    for (int k = 0; k < 4; ++k) {
        int dst = d[k];
        if (dst < plo || dst >= phi) continue;   // not my partition
        int r = atomicAdd(&counts[dst], 1);
        if (r < BUCKET) {
            payload[(size_t)dst * BUCKET + r] = make_int2(s[k], (int)pk[k]);
        } else {
            int o = atomicAdd(ovf_cnt, 1);
            if (o < OVF_CAP) ovf[o] = make_int4(dst, s[k], (int)pk[k], 0);
        }
    }
}

// One wave per node; lane = r*8+c owns the 4 l-elements (shared decay).
// Payload read per edge is wave-uniform -> scalar (s_load) broadcast; no LDS,
// no __syncthreads, waves fully decoupled. Nodes with deg>BUCKET also scan
// the tiny overflow list in-register (replaces the ovf_kernel dispatch).
__global__ __launch_bounds__(256) void gather_bucket_kernel(
    const float* __restrict__ node_feat,     // fp32 [r][l][c] (self term)
    const unsigned short* __restrict__ nfbT, // bf16 [r][c][l]
    const int2* __restrict__ payload,
    const float* __restrict__ prefactor,     // [r][c] = 64
    const float* __restrict__ invr0,         // [r][c] = 64
    const float* __restrict__ coef_p,
    const int* __restrict__ counts,
    const int4* __restrict__ ovf,
    const int* __restrict__ ovf_cnt,
    float* __restrict__ out,
    int n_nodes)
{
    int wave = threadIdx.x >> 6;
    int lane = threadIdx.x & 63;
    int node = blockIdx.x * 4 + wave;
    if (node >= n_nodes) return;

    float iv = invr0[lane] * LOG2E;
    float pf = prefactor[lane];
    float coef = *coef_p;

    int r = lane >> 3, c = lane & 7;
    long obase = (long)node * RLC + r * 32 + c;

    int deg = counts[node];
    int m = deg < BUCKET ? deg : BUCKET;

    // streaming fp32 self-term: non-temporal, don't pollute L2/L3
    float a0 = __builtin_nontemporal_load(node_feat + obase)      * coef;
    float a1 = __builtin_nontemporal_load(node_feat + obase + 8)  * coef;
    float a2 = __builtin_nontemporal_load(node_feat + obase + 16) * coef;
    float a3 = __builtin_nontemporal_load(node_feat + obase + 24) * coef;

    const int2* pp = payload + (size_t)node * BUCKET;
    const unsigned short* tb = nfbT + lane * 4;

    #pragma unroll 4
    for (int it = 0; it < m; ++it) {
        int2 p = pp[it];                           // uniform -> scalar load
        int src = p.x;
        unsigned int pk = (unsigned int)p.y;
        float nl = __half2float(__ushort_as_half((unsigned short)(pk & 0xffff)));
        float cf = __half2float(__ushort_as_half((unsigned short)(pk >> 16)));
        float w = fast_exp2(nl * iv) * pf * cf;    // 1 exp / edge / lane
        uint2 raw = *(const uint2*)(tb + (size_t)src * RLC);
        float f0 = __uint_as_float(raw.x << 16);
        float f1 = __uint_as_float(raw.x & 0xffff0000u);
        float f2 = __uint_as_float(raw.y << 16);
        float f3 = __uint_as_float(raw.y & 0xffff0000u);
        a0 += w * f0; a1 += w * f1; a2 += w * f2; a3 += w * f3;
    }

    if (deg > BUCKET) {
        // rare: fold this node's overflow edges (wave-uniform scan of a
        // tiny L2-resident list; scalar loads broadcast)
        int nov = *ovf_cnt;
        if (nov > OVF_CAP) nov = OVF_CAP;
        for (int i = 0; i < nov; ++i) {
            int4 rec = ovf[i];
            if (rec.x != node) continue;
            unsigned int pk = (unsigned int)rec.z;
            float nl = __half2float(__ushort_as_half((unsigned short)(pk & 0xffff)));
            float cf = __half2float(__ushort_as_half((unsigned short)(pk >> 16)));
            float w = fast_exp2(nl * iv) * pf * cf;
            uint2 raw = *(const uint2*)(tb + (size_t)rec.y * RLC);
            float f0 = __uint_as_float(raw.x << 16);
            float f1 = __uint_as_float(raw.x & 0xffff0000u);
            float f2 = __uint_as_float(raw.y << 16);
            float f3 = __uint_as_float(raw.y & 0xffff0000u);
            a0 += w * f0; a1 += w * f1; a2 += w * f2; a3 += w * f3;
        }
    }

    // streamed output: non-temporal, never re-read
    __builtin_nontemporal_store(a0, out + obase);
    __builtin_nontemporal_store(a1, out + obase + 8);
    __builtin_nontemporal_store(a2, out + obase + 16);
    __builtin_nontemporal_store(a3, out + obase + 24);
}

// ===========================================================================
// TIER 2: R6 CSR path (fallback if ws too small for buckets)
// ===========================================================================

__global__ __launch_bounds__(256) void cast_kernel(
    const float4* __restrict__ in, uint4* __restrict__ outp, int n8)
{
    int i = blockIdx.x * blockDim.x + threadIdx.x;
    if (i >= n8) return;
    float4 a = in[2 * i];
    float4 b = in[2 * i + 1];
    uint4 r;
    r.x = bfr(a.x) | (bfr(a.y) << 16);
    r.y = bfr(a.z) | (bfr(a.w) << 16);
    r.z = bfr(b.x) | (bfr(b.y) << 16);
    r.w = bfr(b.z) | (bfr(b.w) << 16);
    outp[i] = r;
}

__global__ __launch_bounds__(256) void hist_rank_kernel(
    const int* __restrict__ edge_index, int* __restrict__ counts,
    unsigned char* __restrict__ rank, int n_edges)
{
    int e = blockIdx.x * blockDim.x + threadIdx.x;
    if (e >= n_edges) return;
    int dst = edge_index[n_edges + e];
    int r = atomicAdd(&counts[dst], 1);
    rank[e] = (unsigned char)r;
}

__global__ __launch_bounds__(SCAN_BLOCK) void scan1_kernel(
    const int* __restrict__ in, int* __restrict__ out,
    int* __restrict__ blocksums, int n)
{
    __shared__ int tmp[SCAN_BLOCK];
    int t = threadIdx.x;
    int base = blockIdx.x * SCAN_BLOCK * SCAN_ITEMS + t * SCAN_ITEMS;
    int v[SCAN_ITEMS];
    int tot = 0;
    #pragma unroll
    for (int k = 0; k < SCAN_ITEMS; ++k) {
        int i = base + k;
        v[k] = (i < n) ? in[i] : 0;
        tot += v[k];
    }
    tmp[t] = tot;
    __syncthreads();
    int run = tot;
    for (int d = 1; d < SCAN_BLOCK; d <<= 1) {
        int x = (t >= d) ? tmp[t - d] : 0;
        __syncthreads();
        tmp[t] += x;
        __syncthreads();
    }
    int excl = tmp[t] - run;
    #pragma unroll
    for (int k = 0; k < SCAN_ITEMS; ++k) {
        int i = base + k;
        if (i < n) out[i] = excl;
        excl += v[k];
    }
    if (t == SCAN_BLOCK - 1) blocksums[blockIdx.x] = tmp[t];
}

__global__ __launch_bounds__(SCAN_BLOCK) void scan2_kernel(
    int* __restrict__ blocksums, int nb)
{
    __shared__ int tmp[SCAN_BLOCK];
    int t = threadIdx.x;
    int v = (t < nb) ? blocksums[t] : 0;
    tmp[t] = v;
    __syncthreads();
    for (int d = 1; d < SCAN_BLOCK; d <<= 1) {
        int x = (t >= d) ? tmp[t - d] : 0;
        __syncthreads();
        tmp[t] += x;
        __syncthreads();
    }
    if (t < nb) blocksums[t] = tmp[t] - v;
}

__global__ __launch_bounds__(256) void scan3_kernel(
    int* __restrict__ offsets, const int* __restrict__ blocksums,
    int n, int n_edges)
{
    int i = blockIdx.x * blockDim.x + threadIdx.x;
    if (i == 0) offsets[n] = n_edges;
    if (i >= n) return;
    offsets[i] += blocksums[i / (SCAN_BLOCK * SCAN_ITEMS)];
}

__global__ __launch_bounds__(256) void scatter_rank_kernel(
    const int* __restrict__ edge_index,
    const float* __restrict__ edge_len,
    const float* __restrict__ cutoff_fn,
    const int* __restrict__ offsets,
    const unsigned char* __restrict__ rank,
    int2* __restrict__ payload, int n_edges)
{
    int e = blockIdx.x * blockDim.x + threadIdx.x;
    if (e >= n_edges) return;
    int dst = edge_index[n_edges + e];
    int src = edge_index[e];
    unsigned int hnl = __half_as_ushort(__float2half(-edge_len[e]));
    unsigned int hcf = __half_as_ushort(__float2half(cutoff_fn[e]));
    int pos = offsets[dst] + (int)rank[e];
    payload[pos] = make_int2(src, (int)((hcf << 16) | hnl));
}

__global__ __launch_bounds__(256) void gather_kernel(
    const float* __restrict__ node_feat,
    const unsigned short* __restrict__ nfb,
    const int2* __restrict__ payload,
    const float* __restrict__ prefactor,
    const float* __restrict__ invr0,
    const float* __restrict__ coef_p,
    const int*  __restrict__ offsets,
    float* __restrict__ out,
    int n_nodes)
{
    int tid  = blockIdx.x * blockDim.x + threadIdx.x;
    int node = tid >> 6;
    int lane = threadIdx.x & 63;
    if (node >= n_nodes) return;

    int f0     = lane << 2;
    int rcbase = ((f0 >> 5) << 3) + (f0 & 7);

    float4 iv = *(const float4*)(invr0 + rcbase);
    iv.x *= LOG2E; iv.y *= LOG2E; iv.z *= LOG2E; iv.w *= LOG2E;
    const float4 pf = *(const float4*)(prefactor + rcbase);
    float coef = *coef_p;

    const float4 self = *(const float4*)(node_feat + (long)node * RLC + f0);
    float ax = self.x * coef, ay = self.y * coef,
          az = self.z * coef, aw = self.w * coef;

    int j   = offsets[node];
    int end = offsets[node + 1];

    for (int base = j; base < end; base += 64) {
        int idx = base + lane;
        int2 p = make_int2(0, 0);
        if (idx < end) p = payload[idx];
        int m = end - base;
        if (m > 64) m = 64;
        int psrc = p.x;
        int ppk  = p.y;

        #pragma unroll 4
        for (int it = 0; it < m; ++it) {
            int src = __shfl(psrc, it, 64);
            int pk  = __shfl(ppk,  it, 64);
            float nl = __half2float(__ushort_as_half((unsigned short)(pk & 0xffff)));
            float cf = __half2float(__ushort_as_half((unsigned short)(((unsigned int)pk) >> 16)));
            uint2 raw = *(const uint2*)(nfb + (long)src * RLC + f0);
            float fx = __uint_as_float(raw.x << 16);
            float fy = __uint_as_float(raw.x & 0xffff0000u);
            float fz = __uint_as_float(raw.y << 16);
            float fw = __uint_as_float(raw.y & 0xffff0000u);
            ax += fx * (fast_exp2(nl * iv.x) * pf.x * cf);
            ay += fy * (fast_exp2(nl * iv.y) * pf.y * cf);
            az += fz * (fast_exp2(nl * iv.z) * pf.z * cf);
            aw += fw * (fast_exp2(nl * iv.w) * pf.w * cf);
        }
    }

    *(float4*)(out + (long)node * RLC + f0) = make_float4(ax, ay, az, aw);
}

// ===========================================================================
// TIER 3: atomic scatter (no ws)
// ===========================================================================
__global__ __launch_bounds__(256) void init_out_kernel(
    const float4* __restrict__ nf4, float4* __restrict__ out4,
    const float* __restrict__ coef_p, int n4)
{
    int i = blockIdx.x * blockDim.x + threadIdx.x;
    if (i >= n4) return;
    float c = *coef_p;
    float4 v = nf4[i];
    out4[i] = make_float4(v.x * c, v.y * c, v.z * c, v.w * c);
}

__global__ __launch_bounds__(256) void edge_scatter_kernel(
    const float* __restrict__ node_feat,
    const float* __restrict__ edge_len,
    const float* __restrict__ cutoff_fn,
    const int*  __restrict__ edge_index,
    const float* __restrict__ prefactor,
    const float* __restrict__ invr0,
    float* __restrict__ out, int n_edges)
{
    int tid  = blockIdx.x * blockDim.x + threadIdx.x;
    int e    = tid >> 6;
    int lane = threadIdx.x & 63;
    if (e >= n_edges) return;
    int   src = edge_index[e];
    int   dst = edge_index[n_edges + e];
    float len = edge_len[e];
    float cf  = cutoff_fn[e];
    int f0     = lane << 2;
    int rcbase = ((f0 >> 5) << 3) + (f0 & 7);
    const float4 iv = *(const float4*)(invr0 + rcbase);
    const float4 pf = *(const float4*)(prefactor + rcbase);
    const float4 s  = *(const float4*)(node_feat + (long)src * RLC + f0);
    float nl = -len;
    float* o = out + (long)dst * RLC + f0;
    atomicAdd(o + 0, s.x * __expf(nl * iv.x) * pf.x * cf);
    atomicAdd(o + 1, s.y * __expf(nl * iv.y) * pf.y * cf);
    atomicAdd(o + 2, s.z * __expf(nl * iv.z) * pf.z * cf);
    atomicAdd(o + 3, s.w * __expf(nl * iv.w) * pf.w * cf);
}

extern "C" void kernel_launch(void* const* d_in, const int* in_sizes, int n_in,
                              void* d_out, int out_size, void* d_ws, size_t ws_size,
                              hipStream_t stream) {
    const float* node_feat  = (const float*)d_in[0];
    const float* edge_len   = (const float*)d_in[1];
    const float* cutoff_fn  = (const float*)d_in[2];
    const int*   edge_index = (const int*)d_in[3];
    const float* prefactor  = (const float*)d_in[4];
    const float* invr0      = (const float*)d_in[5];
    const float* coef_p     = (const float*)d_in[6];
    float* out = (float*)d_out;

    const int n_edges = in_sizes[1];
    const int n_feat  = in_sizes[0];
    const int n_nodes = n_feat / RLC;

    // TIER 1 layout: nfbT | payload | ovf | counts | ovf_cnt
    size_t need1 = (size_t)n_feat * 2
                 + (size_t)n_nodes * BUCKET * 8
                 + (size_t)OVF_CAP * 16
                 + (size_t)(n_nodes + 1) * 4;

    const int per_block = SCAN_BLOCK * SCAN_ITEMS;
    const int nb1 = (n_nodes + per_block - 1) / per_block;
    size_t need2 = (size_t)n_feat * 2
                 + (size_t)n_edges * 8
                 + ((size_t)(n_nodes + 1) + n_nodes + 256) * 4
                 + (size_t)n_edges;

    if (ws_size >= need1) {
        unsigned short* nfbT = (unsigned short*)d_ws;
        int2* payload = (int2*)(nfbT + n_feat);
        int4* ovf     = (int4*)(payload + (size_t)n_nodes * BUCKET);
        int*  counts  = (int*)(ovf + OVF_CAP);
        int*  ovf_cnt = counts + n_nodes;

        // 1) cast (also zeroes counts+ovf_cnt): nfbT lands in write-back L3;
        //    build's unique footprint (~25MB) won't evict it before gather.
        int nr = n_nodes * 8;
        cast_t_kernel<<<(nr + 255) / 256, 256, 0, stream>>>(
            (const float4*)node_feat, (uint2*)nfbT, nr, counts, n_nodes + 1);

        // 2) build: partition slices stay resident in their XCD L2
        int nb_build = NXCD * ((n_edges + 1023) / 1024);
        build_kernel<<<nb_build, 256, 0, stream>>>(
            edge_index, edge_len, cutoff_fn, counts, payload, ovf, ovf_cnt,
            n_edges, n_nodes);

        // 3) gather (folds overflow edges in-register)
        int gg = (n_nodes + 3) / 4;
        gather_bucket_kernel<<<gg, 256, 0, stream>>>(
            node_feat, nfbT, payload, prefactor, invr0, coef_p, counts,
            ovf, ovf_cnt, out, n_nodes);
    } else if (ws_size >= need2 && nb1 <= SCAN_BLOCK) {
        unsigned short* nfb = (unsigned short*)d_ws;
        int2* payload   = (int2*)(nfb + n_feat);
        int* offsets    = (int*)(payload + n_edges);
        int* counts     = offsets + (n_nodes + 1);
        int* blocksums  = counts + n_nodes;
        unsigned char* rank = (unsigned char*)(blocksums + 256);

        int n8 = n_feat / 8;
        cast_kernel<<<(n8 + 255) / 256, 256, 0, stream>>>(
            (const float4*)node_feat, (uint4*)nfb, n8);

        (void)hipMemsetAsync(counts, 0, (size_t)n_nodes * sizeof(int), stream);

        int eg = (n_edges + 255) / 256;
        hist_rank_kernel<<<eg, 256, 0, stream>>>(edge_index, counts, rank, n_edges);
        scan1_kernel<<<nb1, SCAN_BLOCK, 0, stream>>>(counts, offsets, blocksums, n_nodes);
        scan2_kernel<<<1, SCAN_BLOCK, 0, stream>>>(blocksums, nb1);
        int ng = (n_nodes + 255) / 256;
        scan3_kernel<<<ng, 256, 0, stream>>>(offsets, blocksums, n_nodes, n_edges);
        scatter_rank_kernel<<<eg, 256, 0, stream>>>(
            edge_index, edge_len, cutoff_fn, offsets, rank, payload, n_edges);

        long total = (long)n_nodes * 64;
        int gg = (int)((total + 255) / 256);
        gather_kernel<<<gg, 256, 0, stream>>>(
            node_feat, nfb, payload, prefactor, invr0, coef_p, offsets,
            out, n_nodes);
    } else {
        int n4 = n_feat / 4;
        init_out_kernel<<<(n4 + 255) / 256, 256, 0, stream>>>(
            (const float4*)node_feat, (float4*)out, coef_p, n4);
        long total_threads = (long)n_edges * 64;
        int grid = (int)((total_threads + 255) / 256);
        edge_scatter_kernel<<<grid, 256, 0, stream>>>(
            node_feat, edge_len, cutoff_fn, edge_index,
            prefactor, invr0, out, n_edges);
    }
}